// Round 3
// baseline (178.861 us; speedup 1.0000x reference)
//
#include <hip/hip_runtime.h>

#define BATCH 32
#define NDIM 512
#define LNUM 8
#define KDIM 8

// per-batch workspace layout (float offsets) — slimmed: only what k_big reads
#define WS_PM     0        // int[512]  posmap: node -> pos in S, or -1
#define WS_ACT    640      // float[512] active mask
#define WS_RAT    78976    // float[512*64]  RAT[j][m] = RA[m][j]
#define WS_RDT    111744   // float[512*64]  RDT[j][q] = RD[q][j]
#define WS_STRIDE 144512

#define LSTR 65
typedef float f4 __attribute__((ext_vector_type(4)));

// ---------------------------------------------------------------------------
// k_prep: grid (BATCH, 9).
//   y = 0..7 : RA/RD for 64-column chunk; writes RAT/RDT (ws) AND the S-row
//              entries of out at its non-S columns (D, right, A_rec) directly
//              from registers — no RA/RD round-trip through ws anymore.
//   y = 8    : B2/C2 chain; writes the S x S entries of out directly
//              (predicated p<s, q<s); writes posmap/act to ws.
// Address-disjointness: chunk blocks cover (S-row, non-S-col); y=8 covers
// (S-row, S-col); k_big covers (non-S-row, *). No overlap -> no races.
__global__ __launch_bounds__(256) void k_prep(
    const float* __restrict__ A, const float* __restrict__ O,
    const int* __restrict__ indices, const int* __restrict__ wavelet,
    float* __restrict__ ws, float* __restrict__ out)
{
    const int b  = blockIdx.x;
    const int cy = blockIdx.y;           // 0..8
    const int tid = threadIdx.x;
    float* base = ws + (size_t)b * WS_STRIDE;
    const size_t seg = (size_t)BATCH*NDIM*NDIM;

    __shared__ float Wl[64*LSTR];
    __shared__ __align__(16) float Buf1[64*LSTR];   // AS (chunk, stride 64) / P1,Dmask (y==8)
    __shared__ __align__(16) float Buf2[64*LSTR];   // RAt (chunk, stride 64) / P2 (y==8)
    __shared__ __align__(16) float Buf3[64*LSTR];   // B2 (y==8)
    __shared__ int   pml[NDIM];
    __shared__ float actl[NDIM];
    __shared__ float actS[64];
    __shared__ int   idxsh[64];
    __shared__ int   Ssh[64];
    __shared__ float Oall[LNUM*KDIM*KDIM];
    __shared__ int   s_sh;

    // ---- block-wide staging (no deps) ----
    for (int t = tid; t < LNUM*KDIM*KDIM; t += 256) {
        int l = t >> 6, k = t & 63;
        Oall[t] = O[((size_t)l*BATCH + b)*(KDIM*KDIM) + k];
    }
    if (tid < 64) idxsh[tid] = indices[b*64 + tid];
    for (int n = tid; n < NDIM; n += 256) { pml[n] = -1; actl[n] = 1.f; }
    __syncthreads();                                        // #1

    const int wv = tid >> 6;
    const int ln = tid & 63;
    int s_reg = 0;

    if (wv == 0) {
        // ballot dedup (wave 0 only; all 64 lanes active)
        int n = idxsh[ln];
        bool first = true;
        for (int t = 0; t < ln; ++t) if (idxsh[t] == n) first = false;
        unsigned long long m = __ballot(first);
        int rank = __popcll(m & ((1ull << ln) - 1ull));
        s_reg = (int)__popcll(m);
        if (first) { pml[n] = rank; Ssh[rank] = n; }
        if (ln >= s_reg) Ssh[ln] = 0;                        // pad
        if (ln < LNUM) actl[wavelet[b*LNUM + ln]] = 0.f;
        if (ln == 0) s_sh = s_reg;
    }
    __syncthreads();                                        // #2a: Ssh/pml/actl/s_sh visible

    if (wv == 0) {
        actS[ln] = actl[Ssh[ln]];
        // W init: lane ln owns column ln
        for (int rr = 0; rr < 64; ++rr)
            Wl[rr*LSTR + ln] = (rr == ln && rr < s_reg) ? 1.f : 0.f;
        // 8-level chain, column-local, zero barriers
        for (int l = 0; l < LNUM; ++l) {
            int pr[KDIM];
            float wcol[KDIM], accv[KDIM];
            #pragma unroll
            for (int j = 0; j < KDIM; ++j) pr[j] = pml[idxsh[l*KDIM + j]];
            #pragma unroll
            for (int j = 0; j < KDIM; ++j) wcol[j] = Wl[pr[j]*LSTR + ln];
            #pragma unroll
            for (int i = 0; i < KDIM; ++i) {
                float a = 0.f;
                #pragma unroll
                for (int j = 0; j < KDIM; ++j)
                    a += Oall[l*64 + i*KDIM + j] * wcol[j];
                accv[i] = a;
            }
            #pragma unroll
            for (int i = 0; i < KDIM; ++i) Wl[pr[i]*LSTR + ln] = accv[i];
        }
    } else {
        // waves 1-3: gather A tile concurrently with the chain (needs Ssh only)
        if (cy < 8) {
            const int j0 = cy * 64;
            for (int t = tid - 64; t < 1024; t += 192) {
                int n = t >> 4, cc = t & 15;
                f4 v = ((const f4*)(A + ((size_t)b*NDIM + Ssh[n])*NDIM + j0))[cc];
                ((f4*)(Buf1 + n*64))[cc] = v;               // AS, stride 64
            }
        } else {
            for (int t = tid - 64; t < 4096; t += 192) {
                int n = t >> 6, mm = t & 63;
                Buf1[n*LSTR + mm] = A[((size_t)b*NDIM + Ssh[n])*NDIM + Ssh[mm]];
            }
            int*   g_posmap = (int*)(base + WS_PM);
            float* g_act    = base + WS_ACT;
            for (int n = tid - 64; n < NDIM; n += 192) {
                g_posmap[n] = pml[n]; g_act[n] = actl[n];
            }
        }
    }
    __syncthreads();                                        // #2b: Wl + tile + actS ready
    const int s = s_sh;

    if (cy < 8) {
        // ================= chunk path =====================================
        const int j0 = cy * 64;
        float* AS  = Buf1;               // stride 64
        float* RAt = Buf2;               // stride 64
        float* g_RAT = base + WS_RAT;
        float* g_RDT = base + WS_RDT;

        const int g = wv;
        const int j = ln;
        const int jg = j0 + j;
        const int pj = pml[jg];          // <0 means non-S column
        const float aj = actl[jg];
        float racc[16];

        // pass 1: RA[m][j] = sum_n W[m][n] * AS[n][j]
        #pragma unroll
        for (int k = 0; k < 16; ++k) racc[k] = 0.f;
        for (int n = 0; n < 64; ++n) {
            float av = AS[n*64 + j];
            #pragma unroll
            for (int k = 0; k < 16; ++k) racc[k] += Wl[(g*16 + k)*LSTR + n] * av;
        }
        #pragma unroll
        for (int k = 0; k < 16; ++k) RAt[(g*16 + k)*64 + j] = racc[k];
        {
            f4* dst = (f4*)(g_RAT + (size_t)jg*64 + g*16);
            #pragma unroll
            for (int q = 0; q < 4; ++q) {
                f4 v = { racc[4*q], racc[4*q+1], racc[4*q+2], racc[4*q+3] };
                dst[q] = v;
            }
        }
        // S-row out writes (D and right) at non-S columns, from RA registers
        if (pj < 0) {
            #pragma unroll
            for (int k = 0; k < 16; ++k) {
                int r = g*16 + k;
                if (r < s) {
                    size_t ro = ((size_t)b*NDIM + Ssh[r])*NDIM + jg;
                    out[2*seg + ro] = racc[k] * actS[r] * aj;   // D (i!=j here)
                    out[seg + ro]   = 0.f;                      // right
                }
            }
        }
        __syncthreads();                                    // #3

        // pass 2: RD[q][j] = aj * sum_n W[n][q] * actS[n] * RAt[n][j]
        #pragma unroll
        for (int k = 0; k < 16; ++k) racc[k] = 0.f;
        for (int n = 0; n < 64; ++n) {
            float dt = actS[n] * RAt[n*64 + j];
            #pragma unroll
            for (int k = 0; k < 16; ++k) racc[k] += Wl[n*LSTR + g*16 + k] * dt;
        }
        #pragma unroll
        for (int k = 0; k < 16; ++k) racc[k] *= aj;
        {
            f4* dst = (f4*)(g_RDT + (size_t)jg*64 + g*16);
            #pragma unroll
            for (int q = 0; q < 4; ++q) {
                f4 v = { racc[4*q], racc[4*q+1], racc[4*q+2], racc[4*q+3] };
                dst[q] = v;
            }
        }
        // S-row out writes (A_rec) at non-S columns, from RD registers
        if (pj < 0) {
            #pragma unroll
            for (int k = 0; k < 16; ++k) {
                int r = g*16 + k;
                if (r < s) {
                    size_t ro = ((size_t)b*NDIM + Ssh[r])*NDIM + jg;
                    out[ro] = racc[k];                          // A_rec
                }
            }
        }
    } else {
        // ================= y == 8: B2/C2 + S x S out entries ===============
        const int w = wv;
        float acc[16];

        // T = W * A_SS -> Buf2
        #pragma unroll
        for (int k = 0; k < 16; ++k) acc[k] = 0.f;
        for (int n = 0; n < 64; ++n) {
            float as = Buf1[n*LSTR + ln];
            #pragma unroll
            for (int k = 0; k < 16; ++k) acc[k] += Wl[(w*16 + k)*LSTR + n] * as;
        }
        #pragma unroll
        for (int k = 0; k < 16; ++k) Buf2[(w*16 + k)*LSTR + ln] = acc[k];
        __syncthreads();

        // B2 = T * W^T -> Buf3
        #pragma unroll
        for (int k = 0; k < 16; ++k) acc[k] = 0.f;
        for (int m = 0; m < 64; ++m) {
            float wvv = Wl[ln*LSTR + m];
            #pragma unroll
            for (int k = 0; k < 16; ++k) acc[k] += Buf2[(w*16 + k)*LSTR + m] * wvv;
        }
        #pragma unroll
        for (int k = 0; k < 16; ++k) Buf3[(w*16 + k)*LSTR + ln] = acc[k];
        __syncthreads();

        // D_SS = mask .* B2 -> Buf1
        for (int t = tid; t < 4096; t += 256) {
            int n = t >> 6, m = t & 63;
            float mv = (Ssh[n] == Ssh[m]) ? 1.f : actS[n]*actS[m];
            Buf1[n*LSTR + m] = mv * Buf3[n*LSTR + m];
        }
        __syncthreads();

        // T2 = W^T * D_SS -> Buf2
        #pragma unroll
        for (int k = 0; k < 16; ++k) acc[k] = 0.f;
        for (int n = 0; n < 64; ++n) {
            float dv = Buf1[n*LSTR + ln];
            #pragma unroll
            for (int k = 0; k < 16; ++k) acc[k] += Wl[n*LSTR + (w*16 + k)] * dv;
        }
        #pragma unroll
        for (int k = 0; k < 16; ++k) Buf2[(w*16 + k)*LSTR + ln] = acc[k];
        __syncthreads();

        // C2 = T2 * W (in acc), then write S x S out entries directly
        #pragma unroll
        for (int k = 0; k < 16; ++k) acc[k] = 0.f;
        for (int m = 0; m < 64; ++m) {
            float wvv = Wl[m*LSTR + ln];
            #pragma unroll
            for (int k = 0; k < 16; ++k) acc[k] += Buf2[(w*16 + k)*LSTR + m] * wvv;
        }
        if (ln < s) {
            #pragma unroll
            for (int k = 0; k < 16; ++k) {
                int p = w*16 + k;
                if (p < s) {
                    size_t ro = ((size_t)b*NDIM + Ssh[p])*NDIM + Ssh[ln];
                    out[ro]         = acc[k];               // A_rec = C2
                    out[seg + ro]   = Wl[p*LSTR + ln];      // right = W
                    out[2*seg + ro] = Buf1[p*LSTR + ln];    // D = masked B2
                }
            }
        }
    }
}

// ---------------------------------------------------------------------------
// k_big: non-S rows only (S-rows fully written by k_prep). Zero-LDS float4
// streaming pass; nt hints keep L1/L2 for the reused RAT/RDT/posmap/act.
__global__ __launch_bounds__(256) void k_big(const float* __restrict__ A,
                                             const float* __restrict__ ws,
                                             float* __restrict__ out)
{
    const int b = blockIdx.y;
    const int rh = threadIdx.x >> 7;          // 2 rows per block
    const int lane = threadIdx.x & 127;       // 128 float4s per row
    const int i = blockIdx.x*2 + rh;
    const int j0 = lane*4;

    const float* base = ws + (size_t)b * WS_STRIDE;
    const int*   posmap = (const int*)(base + WS_PM);
    const float* act = base + WS_ACT;
    const float* RAT = base + WS_RAT;
    const float* RDT = base + WS_RDT;

    const int pi = posmap[i];
    if (pi >= 0) return;                      // wave-uniform (rh splits at wave)

    const float acti = act[i];
    const size_t rowoff = ((size_t)b*NDIM + i)*NDIM;
    const size_t seg = (size_t)BATCH*NDIM*NDIM;

    int4   p4  = ((const int4*)posmap)[lane];
    float4 aj4 = ((const float4*)act)[lane];
    int   pm[4] = {p4.x, p4.y, p4.z, p4.w};
    float aj[4] = {aj4.x, aj4.y, aj4.z, aj4.w};

    const float* rat = RAT + (size_t)i*64;    // 256 B, L1-hot per half-block
    const float* rdt = RDT + (size_t)i*64;

    float a[4], arec[4], dv[4], rv[4];
    f4 v = __builtin_nontemporal_load((const f4*)(A + rowoff) + lane);
    a[0]=v.x; a[1]=v.y; a[2]=v.z; a[3]=v.w;
    #pragma unroll
    for (int c = 0; c < 4; ++c) {
        int pj = pm[c];
        if (pj >= 0) a[c] = rat[pj];
        float mv = (i == j0 + c) ? 1.f : acti * aj[c];
        dv[c] = a[c] * mv;
        arec[c] = (pj < 0) ? dv[c] : rdt[pj];
        rv[c] = (i == j0 + c) ? 1.f : 0.f;
    }

    f4 o0; o0.x = arec[0]; o0.y = arec[1]; o0.z = arec[2]; o0.w = arec[3];
    f4 o1; o1.x = rv[0];   o1.y = rv[1];   o1.z = rv[2];   o1.w = rv[3];
    f4 o2; o2.x = dv[0];   o2.y = dv[1];   o2.z = dv[2];   o2.w = dv[3];
    __builtin_nontemporal_store(o0, (f4*)(out + rowoff) + lane);
    __builtin_nontemporal_store(o1, (f4*)(out + seg + rowoff) + lane);
    __builtin_nontemporal_store(o2, (f4*)(out + 2*seg + rowoff) + lane);
}

extern "C" void kernel_launch(void* const* d_in, const int* in_sizes, int n_in,
                              void* d_out, int out_size, void* d_ws, size_t ws_size,
                              hipStream_t stream) {
    const float* A       = (const float*)d_in[0];
    const float* O       = (const float*)d_in[1];
    const int*   indices = (const int*)d_in[2];
    const int*   wavelet = (const int*)d_in[3];
    float* ws  = (float*)d_ws;   // ~18.5 MB layout (RA/RD slots now unused)
    float* out = (float*)d_out;

    k_prep<<<dim3(BATCH, 9), 256, 0, stream>>>(A, O, indices, wavelet, ws, out);
    k_big <<<dim3(NDIM/2, BATCH), 256, 0, stream>>>(A, ws, out);
}